// Round 16
// baseline (1317.626 us; speedup 1.0000x reference)
//
#include <hip/hip_runtime.h>
#include <hip/hip_bf16.h>

typedef _Float16 f16;
typedef _Float16 half8 __attribute__((ext_vector_type(8)));
typedef _Float16 half4 __attribute__((ext_vector_type(4)));
typedef float f32x4 __attribute__((ext_vector_type(4)));
typedef int i32x4 __attribute__((ext_vector_type(4)));

// B=32, S=1024, D=256, H=256, 4H=1024
// Scan r16: i8-MFMA recurrent matmul + LANE-LOCAL gate epilogue.
// Key fact: A = h broadcast across all 16 MFMA rows -> all C rows identical ->
// every lane holds preact(col lane&15, gate g) in acc_g[0] for ALL 4 gates.
// No bpermute, no DPP: each lane runs the full i/f/g/o chain for its col
// (4x redundant across lane groups, free); lanes 0-15 write out + hq.
// 1 lgkm barrier/step, double-buffered h int8 in LDS.

// ---------------- prep: per-column int8 quantization of U (mfma layout) -----
// UQm uint4 index: ((dir*64 + tile)*4 + ks)*64 + kg*16 + colr
//   holds k = ks*64 + kg*16 + {0..15} (16 int8) for col = tile*16 + colr.
__global__ void prep_uq_kernel(const float* __restrict__ Uf, const float* __restrict__ Ur,
                               unsigned int* __restrict__ UQm, float* __restrict__ Uscale)
{
    int idx = blockIdx.x * 256 + threadIdx.x;   // (dir, c)
    if (idx >= 2048) return;
    int dir = idx >> 10, c = idx & 1023;
    const float* U = dir ? Ur : Uf;
    float m = 0.f;
    for (int k = 0; k < 256; ++k) m = fmaxf(m, fabsf(U[k * 1024 + c]));
    float sinv = (m > 0.f) ? 127.f / m : 0.f;
    int tile = c >> 4, colr = c & 15;
    uint4* UQm4 = (uint4*)UQm;
    for (int ks = 0; ks < 4; ++ks) {
        #pragma unroll
        for (int kg = 0; kg < 4; ++kg) {
            unsigned int w[4];
            #pragma unroll
            for (int d = 0; d < 4; ++d) {
                unsigned int wd = 0;
                #pragma unroll
                for (int e = 0; e < 4; ++e) {
                    int k = ks * 64 + kg * 16 + d * 4 + e;
                    int q = __float2int_rn(U[k * 1024 + c] * sinv);
                    wd |= ((unsigned int)(q & 0xff)) << (8 * e);
                }
                w[d] = wd;
            }
            UQm4[((size_t)((dir * 64 + tile) * 4 + ks)) * 64 + kg * 16 + colr] =
                make_uint4(w[0], w[1], w[2], w[3]);
        }
    }
    Uscale[idx] = m / (127.f * 127.f);  // U-scale * h-dequant(1/127)
}

// ---------------- projection GEMM (float4-vectorized staging) ---------------
__global__ __launch_bounds__(256) void proj_gemm_kernel(
    const float* __restrict__ x, const float* __restrict__ Wf, const float* __restrict__ Wr,
    const float* __restrict__ bfw, const float* __restrict__ brw, f16* __restrict__ G)
{
    const int nt = blockIdx.x;
    const int mt = blockIdx.y;
    const int m0 = mt * 128, n0 = nt * 128;
    const int dir = n0 >> 10, nin0 = n0 & 1023;
    const float* W   = dir ? Wr : Wf;
    const float* bia = dir ? brw : bfw;
    __shared__ f16 Asm[128][40];
    __shared__ f16 Bsm[128][40];
    const int t = threadIdx.x;
    const int lane = t & 63, wave = t >> 6;
    const int wr = wave >> 1, wc = wave & 1;
    f32x4 acc[4][4] = {};
    for (int k0 = 0; k0 < 256; k0 += 32) {
        // A: 128x32 f32 -> f16, float4 loads (4/thread)
        #pragma unroll
        for (int e = 0; e < 4; ++e) {
            int f = e * 256 + t;
            int row = f >> 3, quad = f & 7;
            f32x4 v = *(const f32x4*)&x[(size_t)(m0 + row) * 256 + k0 + quad * 4];
            half4 hv; hv[0] = (f16)v[0]; hv[1] = (f16)v[1]; hv[2] = (f16)v[2]; hv[3] = (f16)v[3];
            *(half4*)&Asm[row][quad * 4] = hv;
        }
        // B: 32x128 f32 -> f16 transposed to [col][k], float4 loads (4/thread)
        #pragma unroll
        for (int e = 0; e < 4; ++e) {
            int f = e * 256 + t;
            int kr = f >> 5, colq = f & 31;
            f32x4 v = *(const f32x4*)&W[(size_t)(k0 + kr) * 1024 + nin0 + colq * 4];
            #pragma unroll
            for (int j = 0; j < 4; ++j)
                Bsm[colq * 4 + j][kr] = (f16)v[j];
        }
        __syncthreads();
        const int l15 = lane & 15, kb = (lane >> 4) * 8;
        half8 af[4], bfr[4];
        #pragma unroll
        for (int fr = 0; fr < 4; ++fr) af[fr]  = *(const half8*)&Asm[wr * 64 + fr * 16 + l15][kb];
        #pragma unroll
        for (int fc = 0; fc < 4; ++fc) bfr[fc] = *(const half8*)&Bsm[wc * 64 + fc * 16 + l15][kb];
        #pragma unroll
        for (int fr = 0; fr < 4; ++fr)
            #pragma unroll
            for (int fc = 0; fc < 4; ++fc)
                acc[fr][fc] = __builtin_amdgcn_mfma_f32_16x16x32_f16(af[fr], bfr[fc], acc[fr][fc], 0, 0, 0);
        __syncthreads();
    }
    const int row4 = (lane >> 4) * 4, c15 = lane & 15;
    #pragma unroll
    for (int fr = 0; fr < 4; ++fr)
        #pragma unroll
        for (int fc = 0; fc < 4; ++fc) {
            int rbase = m0 + wr * 64 + fr * 16 + row4;
            int cidx  = n0 + wc * 64 + fc * 16 + c15;
            float bv = bia[cidx & 1023];
            #pragma unroll
            for (int i = 0; i < 4; ++i)
                G[(size_t)(rbase + i) * 2048 + cidx] = (f16)(acc[fr][fc][i] + bv);
        }
}

// ---------------- scan ------------------------------------------------------
__device__ __forceinline__ float sig_fast(float x) {
    return __fdividef(1.f, 1.f + __expf(-x));
}
__device__ __forceinline__ float tanh_fast(float x) {
    float e = __expf(2.f * x);
    return 1.f - __fdividef(2.f, e + 1.f);   // exact limits, NaN-free
}

#define LGKM_BARRIER() do { \
    asm volatile("s_waitcnt lgkmcnt(0)\n\ts_barrier" ::: "memory"); \
    __builtin_amdgcn_sched_barrier(0); \
} while (0)

__global__
__attribute__((amdgpu_flat_work_group_size(1024, 1024)))
__attribute__((amdgpu_waves_per_eu(4, 4)))
void scan_kernel(
    const f16* __restrict__ G, const unsigned int* __restrict__ UQm,
    const float* __restrict__ Uscale, float* __restrict__ out)
{
    const int wg = blockIdx.x;
    const int dir = wg >> 5, b = wg & 31;
    const int tid = threadIdx.x;
    const int wave = tid >> 6, lane = tid & 63;
    const int col16 = wave * 16 + (lane & 15);      // my h-col (x4 replicated)

    __shared__ __align__(16) unsigned int hq[128];  // 2 bufs x 256B int8 h
    if (tid < 64) hq[tid] = 0u;                     // buf0 = h0 = 0

    // B-fragments: gate g of my h-cols -> tile g*16+wave (64 regs, AGPR-ok)
    const i32x4* UQm4 = (const i32x4*)UQm;
    i32x4 uf0[4], uf1[4], uf2[4], uf3[4];
    #pragma unroll
    for (int ks = 0; ks < 4; ++ks) {
        uf0[ks] = UQm4[((size_t)((dir * 64 + ( 0 + wave)) * 4 + ks)) * 64 + lane];
        uf1[ks] = UQm4[((size_t)((dir * 64 + (16 + wave)) * 4 + ks)) * 64 + lane];
        uf2[ks] = UQm4[((size_t)((dir * 64 + (32 + wave)) * 4 + ks)) * 64 + lane];
        uf3[ks] = UQm4[((size_t)((dir * 64 + (48 + wave)) * 4 + ks)) * 64 + lane];
    }

    // per-lane dequant scales for all 4 gates of my col
    const float usc0 = Uscale[dir * 1024 +   0 + col16];
    const float usc1 = Uscale[dir * 1024 + 256 + col16];
    const float usc2 = Uscale[dir * 1024 + 512 + col16];
    const float usc3 = Uscale[dir * 1024 + 768 + col16];

    // xW streams: all 4 gates of my col
    const f16* Gl = G + (size_t)b * 1024 * 2048 + dir * 1024 + col16;
    float* outp = out + (size_t)b * 1024 * 512 + dir * 256 + col16;

    const int s0 = dir ? 1023 : 0;
    float xw0 = (float)Gl[(size_t)s0 * 2048 +   0];
    float xw1 = (float)Gl[(size_t)s0 * 2048 + 256];
    float xw2 = (float)Gl[(size_t)s0 * 2048 + 512];
    float xw3 = (float)Gl[(size_t)s0 * 2048 + 768];
    float c_state = 0.f;
    __syncthreads();

    const char* hqb = (const char*)hq;
    signed char* hqw = (signed char*)hq;
    const int arow = (lane >> 4) << 4;              // A-frag byte offset
    int p = 0;

    for (int t = 0; t < 1024; ++t) {
        const int s  = dir ? (1023 - t) : t;
        const int tn = (t < 1023) ? (t + 1) : t;
        const int sn = dir ? (1023 - tn) : tn;
        f16 xn0 = Gl[(size_t)sn * 2048 +   0];      // prefetch next xW (4 gates)
        f16 xn1 = Gl[(size_t)sn * 2048 + 256];
        f16 xn2 = Gl[(size_t)sn * 2048 + 512];
        f16 xn3 = Gl[(size_t)sn * 2048 + 768];

        // h @ U, exact i32: A = h broadcast across rows; all C rows identical
        i32x4 acc0 = {0,0,0,0}, acc1 = {0,0,0,0}, acc2 = {0,0,0,0}, acc3 = {0,0,0,0};
        #pragma unroll
        for (int ks = 0; ks < 4; ++ks) {
            i32x4 a = *(const i32x4*)(hqb + p * 256 + ks * 64 + arow);
            acc0 = __builtin_amdgcn_mfma_i32_16x16x64_i8(a, uf0[ks], acc0, 0, 0, 0);
            acc1 = __builtin_amdgcn_mfma_i32_16x16x64_i8(a, uf1[ks], acc1, 0, 0, 0);
            acc2 = __builtin_amdgcn_mfma_i32_16x16x64_i8(a, uf2[ks], acc2, 0, 0, 0);
            acc3 = __builtin_amdgcn_mfma_i32_16x16x64_i8(a, uf3[ks], acc3, 0, 0, 0);
        }

        // lane-local gates: acc_g[0] = preact(col16, gate g) on EVERY lane
        float ig = sig_fast((float)acc0[0] * usc0 + xw0);
        float fg = sig_fast((float)acc1[0] * usc1 + xw1);
        float gg = tanh_fast((float)acc2[0] * usc2 + xw2);
        float og = sig_fast((float)acc3[0] * usc3 + xw3);
        c_state = fg * c_state + ig * gg;
        float h = og * tanh_fast(c_state);

        if (lane < 16) {
            outp[(size_t)s * 512] = h;
            hqw[(p ^ 1) * 256 + col16] = (signed char)__float2int_rn(h * 127.f);
        }

        LGKM_BARRIER();                             // new h visible to all
        p ^= 1;
        xw0 = (float)xn0; xw1 = (float)xn1; xw2 = (float)xn2; xw3 = (float)xn3;
    }
}

extern "C" void kernel_launch(void* const* d_in, const int* in_sizes, int n_in,
                              void* d_out, int out_size, void* d_ws, size_t ws_size,
                              hipStream_t stream) {
    const float* x  = (const float*)d_in[0];
    const float* Wf = (const float*)d_in[1];
    const float* Uf = (const float*)d_in[2];
    const float* bf = (const float*)d_in[3];
    const float* Wr = (const float*)d_in[4];
    const float* Ur = (const float*)d_in[5];
    const float* br = (const float*)d_in[6];
    float* out = (float*)d_out;

    char* ws = (char*)d_ws;
    unsigned int* UQm = (unsigned int*)ws;                      // 512 KB
    float* Uscale     = (float*)(ws + (size_t)512 * 1024);      // 8 KB
    f16* G            = (f16*)(ws + (size_t)1024 * 1024);       // 128 MB

    prep_uq_kernel<<<8, 256, 0, stream>>>(Uf, Ur, UQm, Uscale);
    dim3 gg(16, 256);
    proj_gemm_kernel<<<gg, 256, 0, stream>>>(x, Wf, Wr, bf, br, G);
    scan_kernel<<<64, 1024, 0, stream>>>(G, UQm, Uscale, out);
}

// Round 17
// 995.497 us; speedup vs baseline: 1.3236x; 1.3236x over previous
//
#include <hip/hip_runtime.h>
#include <hip/hip_bf16.h>

typedef _Float16 f16;
typedef _Float16 half8 __attribute__((ext_vector_type(8)));
typedef float f32x4 __attribute__((ext_vector_type(4)));
typedef int i32x4 __attribute__((ext_vector_type(4)));

// B=32, S=1024, D=256, H=256, 4H=1024
// Scan (r15 optimum): i8-MFMA recurrent matmul, quad-gate epilogue,
// 1 lgkm-barrier/step, double-buffered h.
// Wave w owns tiles {g*16+w} (all 4 gates of h-cols w*16..w*16+15).
// Lane l = gate (l&3) of h-col w*16+(l>>2); quads combine via DPP quad_perm.
// Epilogue redistribution: all 64 lanes hold identical C rows, so lane group
// a=l>>4 pre-selects acc_a locally (3 cndmask) and one ds_bpermute pulls
// (col l>>2, gate l&3) from lane (l&3)*16 + (l>>2).

// ---------------- prep: per-column int8 quantization of U (mfma layout) -----
// UQm uint4 index: ((dir*64 + tile)*4 + ks)*64 + kg*16 + colr
//   holds k = ks*64 + kg*16 + {0..15} (16 int8) for col = tile*16 + colr.
__global__ void prep_uq_kernel(const float* __restrict__ Uf, const float* __restrict__ Ur,
                               unsigned int* __restrict__ UQm, float* __restrict__ Uscale)
{
    int idx = blockIdx.x * 256 + threadIdx.x;   // (dir, c)
    if (idx >= 2048) return;
    int dir = idx >> 10, c = idx & 1023;
    const float* U = dir ? Ur : Uf;
    float m = 0.f;
    for (int k = 0; k < 256; ++k) m = fmaxf(m, fabsf(U[k * 1024 + c]));
    float sinv = (m > 0.f) ? 127.f / m : 0.f;
    int tile = c >> 4, colr = c & 15;
    uint4* UQm4 = (uint4*)UQm;
    for (int ks = 0; ks < 4; ++ks) {
        #pragma unroll
        for (int kg = 0; kg < 4; ++kg) {
            unsigned int w[4];
            #pragma unroll
            for (int d = 0; d < 4; ++d) {
                unsigned int wd = 0;
                #pragma unroll
                for (int e = 0; e < 4; ++e) {
                    int k = ks * 64 + kg * 16 + d * 4 + e;
                    int q = __float2int_rn(U[k * 1024 + c] * sinv);
                    wd |= ((unsigned int)(q & 0xff)) << (8 * e);
                }
                w[d] = wd;
            }
            UQm4[((size_t)((dir * 64 + tile) * 4 + ks)) * 64 + kg * 16 + colr] =
                make_uint4(w[0], w[1], w[2], w[3]);
        }
    }
    Uscale[idx] = m / (127.f * 127.f);  // U-scale * h-dequant(1/127)
}

// ---------------- projection GEMM (proven r15 version) ----------------------
__global__ __launch_bounds__(256) void proj_gemm_kernel(
    const float* __restrict__ x, const float* __restrict__ Wf, const float* __restrict__ Wr,
    const float* __restrict__ bfw, const float* __restrict__ brw, f16* __restrict__ G)
{
    const int nt = blockIdx.x;
    const int mt = blockIdx.y;
    const int m0 = mt * 128, n0 = nt * 128;
    const int dir = n0 >> 10, nin0 = n0 & 1023;
    const float* W   = dir ? Wr : Wf;
    const float* bia = dir ? brw : bfw;
    __shared__ f16 Asm[128][40];
    __shared__ f16 Bsm[128][40];
    const int t = threadIdx.x;
    const int lane = t & 63, wave = t >> 6;
    const int wr = wave >> 1, wc = wave & 1;
    f32x4 acc[4][4] = {};
    for (int k0 = 0; k0 < 256; k0 += 32) {
        #pragma unroll
        for (int e = 0; e < 16; ++e) {
            int idx = e * 256 + t;
            int r = idx >> 5, kk = idx & 31;
            Asm[r][kk] = (f16)x[(size_t)(m0 + r) * 256 + (k0 + kk)];
        }
        #pragma unroll
        for (int e = 0; e < 16; ++e) {
            int idx = e * 256 + t;
            int col = idx & 127, kr = idx >> 7;
            Bsm[col][kr] = (f16)W[(size_t)(k0 + kr) * 1024 + (nin0 + col)];
        }
        __syncthreads();
        const int l15 = lane & 15, kb = (lane >> 4) * 8;
        half8 af[4], bfr[4];
        #pragma unroll
        for (int fr = 0; fr < 4; ++fr) af[fr]  = *(const half8*)&Asm[wr * 64 + fr * 16 + l15][kb];
        #pragma unroll
        for (int fc = 0; fc < 4; ++fc) bfr[fc] = *(const half8*)&Bsm[wc * 64 + fc * 16 + l15][kb];
        #pragma unroll
        for (int fr = 0; fr < 4; ++fr)
            #pragma unroll
            for (int fc = 0; fc < 4; ++fc)
                acc[fr][fc] = __builtin_amdgcn_mfma_f32_16x16x32_f16(af[fr], bfr[fc], acc[fr][fc], 0, 0, 0);
        __syncthreads();
    }
    const int row4 = (lane >> 4) * 4, c15 = lane & 15;
    #pragma unroll
    for (int fr = 0; fr < 4; ++fr)
        #pragma unroll
        for (int fc = 0; fc < 4; ++fc) {
            int rbase = m0 + wr * 64 + fr * 16 + row4;
            int cidx  = n0 + wc * 64 + fc * 16 + c15;
            float bv = bia[cidx & 1023];
            #pragma unroll
            for (int i = 0; i < 4; ++i)
                G[(size_t)(rbase + i) * 2048 + cidx] = (f16)(acc[fr][fc][i] + bv);
        }
}

// ---------------- scan ------------------------------------------------------
template<int PAT>
__device__ __forceinline__ float qb(float v) {   // quad_perm broadcast
    return __int_as_float(__builtin_amdgcn_mov_dpp(__float_as_int(v), PAT, 0xF, 0xF, true));
}

#define LGKM_BARRIER() do { \
    asm volatile("s_waitcnt lgkmcnt(0)\n\ts_barrier" ::: "memory"); \
    __builtin_amdgcn_sched_barrier(0); \
} while (0)

__global__
__attribute__((amdgpu_flat_work_group_size(1024, 1024)))
__attribute__((amdgpu_waves_per_eu(4, 4)))
void scan_kernel(
    const f16* __restrict__ G, const unsigned int* __restrict__ UQm,
    const float* __restrict__ Uscale, float* __restrict__ out)
{
    const int wg = blockIdx.x;
    const int dir = wg >> 5, b = wg & 31;
    const int tid = threadIdx.x;
    const int wave = tid >> 6, lane = tid & 63;
    const int colq = lane >> 2, gate = lane & 3;    // lane -> (col, gate)
    const int mycol = wave * 16 + colq;

    __shared__ __align__(16) unsigned int hq[128];  // 2 bufs x 256B int8 h

    if (tid < 64) hq[tid] = 0u;                     // buf0 = h0 = 0

    // B-fragments: gate g of my h-cols -> tile g*16+wave (64 regs, AGPR-ok)
    const i32x4* UQm4 = (const i32x4*)UQm;
    i32x4 uf0[4], uf1[4], uf2[4], uf3[4];
    #pragma unroll
    for (int ks = 0; ks < 4; ++ks) {
        uf0[ks] = UQm4[((size_t)((dir * 64 + ( 0 + wave)) * 4 + ks)) * 64 + lane];
        uf1[ks] = UQm4[((size_t)((dir * 64 + (16 + wave)) * 4 + ks)) * 64 + lane];
        uf2[ks] = UQm4[((size_t)((dir * 64 + (32 + wave)) * 4 + ks)) * 64 + lane];
        uf3[ks] = UQm4[((size_t)((dir * 64 + (48 + wave)) * 4 + ks)) * 64 + lane];
    }

    // per-lane dequant scale for (gate, mycol)
    const float uscl = Uscale[dir * 1024 + gate * 256 + mycol];

    // per-lane xW stream: G[s][dir*1024 + gate*256 + mycol]
    const f16* Gl = G + (size_t)b * 1024 * 2048 + dir * 1024 + gate * 256 + mycol;
    float* outp = out + (size_t)b * 1024 * 512 + dir * 256 + mycol;

    const int s0 = dir ? 1023 : 0;
    float xw = (float)Gl[(size_t)s0 * 2048];
    float c_state = 0.f;                            // replicated per quad
    __syncthreads();

    const char* hqb = (const char*)hq;
    signed char* hqw = (signed char*)hq;
    const int arow = (lane >> 4) << 4;              // A-frag byte offset
    const int baddr = ((gate << 4) | colq) << 2;    // pull from lane gate*16+colq
    int p = 0;

    for (int t = 0; t < 1024; ++t) {
        const int s  = dir ? (1023 - t) : t;
        const int tn = (t < 1023) ? (t + 1) : t;
        const int sn = dir ? (1023 - tn) : tn;
        f16 xn = Gl[(size_t)sn * 2048];             // prefetch next xW

        // h @ U, exact i32: A = h broadcast across rows; all C rows identical
        i32x4 acc0 = {0,0,0,0}, acc1 = {0,0,0,0}, acc2 = {0,0,0,0}, acc3 = {0,0,0,0};
        #pragma unroll
        for (int ks = 0; ks < 4; ++ks) {
            i32x4 a = *(const i32x4*)(hqb + p * 256 + ks * 64 + arow);
            acc0 = __builtin_amdgcn_mfma_i32_16x16x64_i8(a, uf0[ks], acc0, 0, 0, 0);
            acc1 = __builtin_amdgcn_mfma_i32_16x16x64_i8(a, uf1[ks], acc1, 0, 0, 0);
            acc2 = __builtin_amdgcn_mfma_i32_16x16x64_i8(a, uf2[ks], acc2, 0, 0, 0);
            acc3 = __builtin_amdgcn_mfma_i32_16x16x64_i8(a, uf3[ks], acc3, 0, 0, 0);
        }

        // every lane holds acc_g[0] = pre(col lane&15, gate g) for g=0..3.
        // Lane group a = lane>>4 pre-selects acc_a; lane l pulls its
        // (col l>>2, gate l&3) from lane (l&3)*16 + (l>>2): 1 bpermute total.
        int sel01 = (lane & 16) ? acc1[0] : acc0[0];
        int sel23 = (lane & 16) ? acc3[0] : acc2[0];
        int sgv   = (lane & 32) ? sel23 : sel01;
        int iv = __builtin_amdgcn_ds_bpermute(baddr, sgv);

        float pre = (float)iv * uscl + xw;
        // unified nonlinearity: gate 2 -> tanh, else sigmoid
        float a2 = (gate == 2) ? (pre + pre) : -pre;
        float E  = __expf(a2);
        float r  = __fdividef(1.f, E + 1.f);
        float v  = (gate == 2) ? (1.f - 2.f * r) : r;
        // quad combine: b0=sig_i, b1=sig_f, b2=tanh_g, b3=sig_o
        float b0 = qb<0x00>(v), b1 = qb<0x55>(v), b2 = qb<0xAA>(v), b3 = qb<0xFF>(v);
        c_state = b1 * c_state + b0 * b2;
        float e2 = __expf(c_state + c_state);
        float th = 1.f - __fdividef(2.f, e2 + 1.f);
        float h  = b3 * th;

        if (gate == 0) outp[(size_t)s * 512] = h;
        if (gate == 1) hqw[(p ^ 1) * 256 + mycol] = (signed char)__float2int_rn(h * 127.f);

        LGKM_BARRIER();                             // new h visible to all
        p ^= 1;
        xw = (float)xn;
    }
}

extern "C" void kernel_launch(void* const* d_in, const int* in_sizes, int n_in,
                              void* d_out, int out_size, void* d_ws, size_t ws_size,
                              hipStream_t stream) {
    const float* x  = (const float*)d_in[0];
    const float* Wf = (const float*)d_in[1];
    const float* Uf = (const float*)d_in[2];
    const float* bf = (const float*)d_in[3];
    const float* Wr = (const float*)d_in[4];
    const float* Ur = (const float*)d_in[5];
    const float* br = (const float*)d_in[6];
    float* out = (float*)d_out;

    char* ws = (char*)d_ws;
    unsigned int* UQm = (unsigned int*)ws;                      // 512 KB
    float* Uscale     = (float*)(ws + (size_t)512 * 1024);      // 8 KB
    f16* G            = (f16*)(ws + (size_t)1024 * 1024);       // 128 MB

    prep_uq_kernel<<<8, 256, 0, stream>>>(Uf, Ur, UQm, Uscale);
    dim3 gg(16, 256);
    proj_gemm_kernel<<<gg, 256, 0, stream>>>(x, Wf, Wr, bf, br, G);
    scan_kernel<<<64, 1024, 0, stream>>>(G, UQm, Uscale, out);
}